// Round 13
// baseline (241.706 us; speedup 1.0000x reference)
//
#include <hip/hip_runtime.h>
#include <math.h>

#define BATCH 4
#define SEQ   2048
#define DMODEL 1024
#define HEADS 16
#define DHEAD 64
#define SCALE 0.03125f                 // DIM^-0.5 = 1/32
#define KEXP  0.045084220027780106f    // SCALE * log2(e)
#define QKV_ELEMS (BATCH * HEADS * SEQ * DHEAD)  // 8388608 per tensor

typedef __attribute__((ext_vector_type(8))) short short8;
typedef __attribute__((ext_vector_type(4))) float floatx4;
typedef unsigned int u32;

__device__ __forceinline__ unsigned short f2bf(float f) {
  union { float f; unsigned u; } v;
  v.f = f;
  return (unsigned short)((v.u + 0x7FFFu + ((v.u >> 16) & 1u)) >> 16);
}

__device__ __forceinline__ float fast_exp2(float x) {
#if __has_builtin(__builtin_amdgcn_exp2f)
  return __builtin_amdgcn_exp2f(x);
#else
  return __expf(x * 0.6931471805599453f);
#endif
}

// pack two fp32 -> bf16x2 in one u32 (low = p0, high = p1)
__device__ __forceinline__ u32 pack_bf16(float p0, float p1) {
#if __has_builtin(__builtin_amdgcn_cvt_pk_bf16_f32)
  typedef __bf16 bf16x2 __attribute__((ext_vector_type(2)));
  bf16x2 t = __builtin_amdgcn_cvt_pk_bf16_f32(p0, p1);
  u32 r;
  __builtin_memcpy(&r, &t, 4);
  return r;
#else
  u32 a0 = __float_as_uint(p0) + 0x8000u;
  u32 a1 = __float_as_uint(p1) + 0x8000u;
  return __builtin_amdgcn_perm(a1, a0, 0x07060302);
#endif
}

// async global->LDS, 16B per lane; lds dest is wave-uniform base + lane*16.
__device__ __forceinline__ void async_ld16(const void* g, void* l) {
  __builtin_amdgcn_global_load_lds(
      (const __attribute__((address_space(1))) u32*)g,
      (__attribute__((address_space(3))) u32*)l, 16, 0, 0);
}

// ---------------------------------------------------------------------------
// Merged prep: x->bf16 (blocks 0..8191), wqkv transpose (8192..11263),
// wout transpose (11264..12287).
// ---------------------------------------------------------------------------
__device__ __forceinline__ void trans_tile(const float* __restrict__ W,
                                           unsigned short* __restrict__ WT,
                                           int K, int N, int n0, int k0,
                                           float (*tile)[33]) {
  const int tx = threadIdx.x & 31, ty = threadIdx.x >> 5;  // ty 0..7
#pragma unroll
  for (int i = 0; i < 4; ++i)
    tile[ty + i * 8][tx] = W[(size_t)(k0 + ty + i * 8) * N + n0 + tx];
  __syncthreads();
#pragma unroll
  for (int i = 0; i < 4; ++i)
    WT[(size_t)(n0 + ty + i * 8) * K + k0 + tx] = f2bf(tile[tx][ty + i * 8]);
}

__global__ __launch_bounds__(256) void prep_kernel(
    const float* __restrict__ x, const float* __restrict__ wqkv,
    const float* __restrict__ wout, unsigned short* __restrict__ xb,
    unsigned short* __restrict__ wqkvT, unsigned short* __restrict__ woutT) {
  __shared__ float tile[32][33];
  const int bx = blockIdx.x;
  if (bx < 8192) {
    size_t i = ((size_t)bx * 256 + threadIdx.x) * 4;
    float4 v = *(const float4*)(x + i);
    ushort4 o;
    o.x = f2bf(v.x); o.y = f2bf(v.y); o.z = f2bf(v.z); o.w = f2bf(v.w);
    *(ushort4*)(xb + i) = o;
  } else if (bx < 11264) {
    int t = bx - 8192;
    trans_tile(wqkv, wqkvT, 1024, 3072, (t % 96) * 32, (t / 96) * 32, tile);
  } else {
    int t = bx - 11264;
    trans_tile(wout, woutT, 1024, 1024, (t % 32) * 32, (t / 32) * 32, tile);
  }
}

// ---------------------------------------------------------------------------
// BK=64 GEMM core (used by gemm_out): 256x128 tile, 512 threads, triple-
// buffered 144KB LDS, counted vmcnt(6). 1 block/CU — fine for gemm_out whose
// grid (256) is exactly one round anyway.
// ---------------------------------------------------------------------------
#define G_BAR() __builtin_amdgcn_s_barrier()
#define G_LGKM0() asm volatile("s_waitcnt lgkmcnt(0)" ::: "memory")

#define STAGE_TILE(t)                                                          \
  do {                                                                         \
    const unsigned short* Ab =                                                 \
        A + (size_t)(m0 + srow) * 1024 + (t) * 64 + schunk * 8;                \
    const unsigned short* Bb =                                                 \
        BT + (size_t)(n0 + srow) * 1024 + (t) * 64 + schunk * 8;               \
    unsigned short* sa = smemS + ((t) % 3) * 24576;                            \
    unsigned short* sb = sa + 16384;                                           \
    async_ld16(Ab, sa + tid * 8);                                              \
    async_ld16(Ab + 64 * 1024, sa + 4096 + tid * 8);                           \
    async_ld16(Ab + 128 * 1024, sa + 8192 + tid * 8);                          \
    async_ld16(Ab + 192 * 1024, sa + 12288 + tid * 8);                         \
    async_ld16(Bb, sb + tid * 8);                                              \
    async_ld16(Bb + 64 * 1024, sb + 4096 + tid * 8);                           \
  } while (0)

#define RD_A(SAp, mh)                                                          \
  do {                                                                         \
    _Pragma("unroll") for (int mi = 0; mi < 4; ++mi) {                         \
      a[mi][0] = *(const short8*)((SAp) + rowA + (mh)*4096 + mi * 1024 + cof0);\
      a[mi][1] = *(const short8*)((SAp) + rowA + (mh)*4096 + mi * 1024 + cof1);\
    }                                                                          \
  } while (0)

#define RD_B(SBp)                                                              \
  do {                                                                         \
    _Pragma("unroll") for (int ni = 0; ni < 2; ++ni) {                         \
      b[ni][0] = *(const short8*)((SBp) + rowB + ni * 1024 + cof0);            \
      b[ni][1] = *(const short8*)((SBp) + rowB + ni * 1024 + cof1);            \
    }                                                                          \
  } while (0)

#define CLUSTER(mh)                                                            \
  do {                                                                         \
    __builtin_amdgcn_s_setprio(1);                                             \
    _Pragma("unroll") for (int mi = 0; mi < 4; ++mi) {                         \
      _Pragma("unroll") for (int ni = 0; ni < 2; ++ni) {                       \
        acc[(mh)*4 + mi][ni] = __builtin_amdgcn_mfma_f32_16x16x32_bf16(        \
            a[mi][0], b[ni][0], acc[(mh)*4 + mi][ni], 0, 0, 0);                \
        acc[(mh)*4 + mi][ni] = __builtin_amdgcn_mfma_f32_16x16x32_bf16(        \
            a[mi][1], b[ni][1], acc[(mh)*4 + mi][ni], 0, 0, 0);                \
      }                                                                        \
    }                                                                          \
    __builtin_amdgcn_s_setprio(0);                                             \
  } while (0)

__device__ __forceinline__ void core256x128(
    const unsigned short* __restrict__ A, const unsigned short* __restrict__ BT,
    unsigned short* smemS, int m0, int n0, floatx4 (&acc)[8][2]) {
  const int tid = threadIdx.x;            // 0..511
  const int wave = tid >> 6, lane = tid & 63;
  const int Q4 = lane >> 4, L = lane & 15;
  const int wr = wave >> 2, wc = wave & 3;
  const int srow = tid >> 3;                   // 0..63
  const int schunk = (tid & 7) ^ (srow & 7);   // swizzled k-chunk
  const int xorL = L & 7;
  const int cof0 = (Q4 ^ xorL) * 8;
  const int cof1 = ((4 + Q4) ^ xorL) * 8;
  const int rowA = wr * 8192 + L * 64;         // wave M-half base (rows*64)
  const int rowB = wc * 2048 + L * 64;         // wave N-slab base

  short8 a[4][2], b[2][2];
#pragma unroll
  for (int mt = 0; mt < 8; ++mt)
#pragma unroll
    for (int nt = 0; nt < 2; ++nt) acc[mt][nt] = (floatx4){0.f, 0.f, 0.f, 0.f};

  STAGE_TILE(0);
  STAGE_TILE(1);
  asm volatile("s_waitcnt vmcnt(6)" ::: "memory");
  G_BAR();

#pragma unroll
  for (int u = 0; u < 16; ++u) {
    unsigned short* SA = smemS + (u % 3) * 24576;
    unsigned short* SB = SA + 16384;
    // ---- Ph1: read A(mh0)+B of tile u; stage tile u+2
    RD_A(SA, 0);
    RD_B(SB);
    if (u + 2 < 16) STAGE_TILE(u + 2);
    G_BAR(); G_LGKM0();
    CLUSTER(0);
    G_BAR();
    // ---- Ph2: read A(mh1); counted vmcnt before closing barrier
    RD_A(SA, 1);
    G_BAR(); G_LGKM0();
    CLUSTER(1);
    if (u + 2 < 16) asm volatile("s_waitcnt vmcnt(6)" ::: "memory");
    else            asm volatile("s_waitcnt vmcnt(0)" ::: "memory");
    G_BAR();
  }
}

// ---------------------------------------------------------------------------
// BK=32 GEMM core (used by gemm_qkv): 256x128 tile, 512 threads, TRIPLE-
// buffered 72KB LDS -> 2 BLOCKS/CU (R12 diagnosis: qkv at 144KB = 1 block/CU
// was latency-bound at MfmaUtil 26%, Occupancy 20% — no co-resident block to
// hide the per-phase vmcnt+barrier stall; m114 cross-block overlap is what
// made the m97 structure hit 912 TF at 3 blocks/CU).
// Per K-step: 10 ds_read_b128 + 16 MFMA in one barrier pair; stage tile u+2
// (3 global_load_lds); counted vmcnt(3): at phase u end outstanding =
// S(u+1)(3)+S(u+2)(3) -> wait 3 completes S(u+1) before phase u+1 reads it.
// WAR: buf[(u+2)%3] last read in phase u-1, closing barrier precedes stage.
// K consumed in the same sequential order (one 32-chunk per MFMA) ->
// bitwise-identical output. Swizzle: source-side (tid&3)^(row&3), read-side
// (quad^(row&3)) — same involution both sides (rule #21).
// ---------------------------------------------------------------------------
#define K32_STAGE(t)                                                           \
  do {                                                                         \
    const unsigned short* Ab =                                                 \
        A + (size_t)(m0 + rA) * 1024 + (t) * 32 + cS;                          \
    const unsigned short* Bb =                                                 \
        BT + (size_t)(n0 + rA) * 1024 + (t) * 32 + cS;                         \
    unsigned short* sa = smemS + ((t) % 3) * 12288;                            \
    unsigned short* sb = sa + 8192;                                            \
    async_ld16(Ab, sa + tid * 8);                                              \
    async_ld16(Ab + 128 * 1024, sa + 4096 + tid * 8);                          \
    async_ld16(Bb, sb + tid * 8);                                              \
  } while (0)

__device__ __forceinline__ void core256x128_k32(
    const unsigned short* __restrict__ A, const unsigned short* __restrict__ BT,
    unsigned short* smemS, int m0, int n0, floatx4 (&acc)[8][2]) {
  const int tid = threadIdx.x;            // 0..511
  const int wave = tid >> 6, lane = tid & 63;
  const int Q4 = lane >> 4, L = lane & 15;
  const int wr = wave >> 2, wc = wave & 3;
  const int rA = tid >> 2;                       // staging row 0..127
  const int cS = ((tid & 3) ^ (rA & 3)) * 8;     // swizzled k-chunk (shorts)
  const int xq = (Q4 ^ (L & 3)) * 8;             // read-side k-chunk offset
  const int rowA = wr * 4096 + L * 32;           // shorts
  const int rowB = wc * 1024 + L * 32;           // shorts

  short8 a[8], b[2];
#pragma unroll
  for (int mt = 0; mt < 8; ++mt)
#pragma unroll
    for (int nt = 0; nt < 2; ++nt) acc[mt][nt] = (floatx4){0.f, 0.f, 0.f, 0.f};

  K32_STAGE(0);
  K32_STAGE(1);
  asm volatile("s_waitcnt vmcnt(3)" ::: "memory");
  G_BAR();

#pragma unroll
  for (int u = 0; u < 32; ++u) {
    unsigned short* SA = smemS + (u % 3) * 12288;
    unsigned short* SB = SA + 8192;
#pragma unroll
    for (int mt = 0; mt < 8; ++mt)
      a[mt] = *(const short8*)(SA + rowA + mt * 512 + xq);
#pragma unroll
    for (int nt = 0; nt < 2; ++nt)
      b[nt] = *(const short8*)(SB + rowB + nt * 512 + xq);
    if (u + 2 < 32) K32_STAGE(u + 2);
    G_BAR(); G_LGKM0();
    __builtin_amdgcn_s_setprio(1);
#pragma unroll
    for (int mt = 0; mt < 8; ++mt)
#pragma unroll
      for (int nt = 0; nt < 2; ++nt)
        acc[mt][nt] = __builtin_amdgcn_mfma_f32_16x16x32_bf16(
            a[mt], b[nt], acc[mt][nt], 0, 0, 0);
    __builtin_amdgcn_s_setprio(0);
    if (u + 2 < 32) asm volatile("s_waitcnt vmcnt(3)" ::: "memory");
    else            asm volatile("s_waitcnt vmcnt(0)" ::: "memory");
    G_BAR();
  }
}

// ---------------------------------------------------------------------------
// QKV GEMM: grid 32x24 = 768 blocks; BK=32 core at 2 blocks/CU (512
// co-resident slots -> 1.5 scheduling rounds, cross-block overlap hides the
// per-phase stalls). nblk 0..7 -> Q (scaled by KEXP), 8..15 -> K (repacked
// to [B,H,N,64] rows), 16..23 -> V transposed into vtg [B,H,64,N]
// (pc-permuted tokens).
// ---------------------------------------------------------------------------
__global__ __launch_bounds__(512, 4) void gemm_qkv_kernel(
    const unsigned short* __restrict__ A, const unsigned short* __restrict__ BT,
    unsigned short* __restrict__ qk, unsigned short* __restrict__ vtg) {
  __shared__ __align__(16) unsigned char smem[73728];  // 3 x 24KB
  unsigned short* smemS = (unsigned short*)smem;

  const int tid = threadIdx.x;
  const int wave = tid >> 6, lane = tid & 63;
  const int Q4 = lane >> 4, L = lane & 15;
  const int wr = wave >> 2, wc = wave & 3;

  // bijective XCD swizzle over 768 blocks (768 % 8 == 0)
  const int flat = blockIdx.y * 24 + blockIdx.x;
  const int swz = (flat & 7) * 96 + (flat >> 3);
  const int mblk = swz / 24, nblk = swz % 24;
  const int m0 = mblk * 256, n0 = nblk * 128;

  floatx4 acc[8][2];
  core256x128_k32(A, BT, smemS, m0, n0, acc);

  // ------------------------------- epilogue -------------------------------
  const int bb = m0 >> 11;
  const int ntok0 = m0 & 2047;
  unsigned short* T = smemS;

  if (nblk < 16) {
    // Q/K: repack to [B,H,N,64] rows via T[256][136] (single pass)
    const float qsc = (nblk < 8) ? KEXP : 1.0f;
    unsigned short* dst = qk + (size_t)(nblk >> 3) * QKV_ELEMS;
    const int h0 = (nblk & 7) * 2;
#pragma unroll
    for (int mt = 0; mt < 8; ++mt)
#pragma unroll
      for (int nt = 0; nt < 2; ++nt) {
        const int col = wc * 32 + nt * 16 + L;
        const int tokl = wr * 128 + mt * 16 + Q4 * 4;
#pragma unroll
        for (int r = 0; r < 4; ++r)
          T[(tokl + r) * 136 + col] = f2bf(acc[mt][nt][r] * qsc);
      }
    __syncthreads();
#pragma unroll
    for (int it2 = 0; it2 < 8; ++it2) {
      int slot = it2 * 512 + tid;
      int tok = slot >> 4, ch = slot & 15;
      int hh = ch >> 3, inner = ch & 7;
      *(short8*)(dst +
                 (((size_t)((bb * 16 + h0 + hh) * 2048 + ntok0 + tok)) << 6) +
                 inner * 8) = *(const short8*)&T[tok * 136 + hh * 64 + inner * 8];
    }
  } else {
    // V: transpose to vtg [B,H,64,N] with pc-permuted tokens via T[128][264]
    const int nv0 = (nblk - 16) * 128;
#pragma unroll
    for (int mt = 0; mt < 8; ++mt)
#pragma unroll
      for (int nt = 0; nt < 2; ++nt) {
        const int col = wc * 32 + nt * 16 + L;
#pragma unroll
        for (int r = 0; r < 4; ++r) {
          int tok = wr * 128 + mt * 16 + Q4 * 4 + r;
          int pcm = (tok & ~31) | ((tok & 15) << 1) | ((tok >> 4) & 1);
          T[col * 264 + pcm] = f2bf(acc[mt][nt][r]);
        }
      }
    __syncthreads();
#pragma unroll
    for (int it2 = 0; it2 < 8; ++it2) {
      int slot = it2 * 512 + tid;
      int col = slot >> 5, ch = slot & 31;
      int nc = nv0 + col;
      *(short8*)(vtg +
                 (((size_t)((bb * 16 + (nc >> 6)) * 64 + (nc & 63))) << 11) +
                 ntok0 + ch * 8) = *(const short8*)&T[col * 264 + ch * 8];
    }
  }
}

// ---------------------------------------------------------------------------
// Output GEMM: grid 32x8 = 256 blocks (exactly 1 full round of 256 CUs).
// Keeps the proven BK=64 core (2 blocks/CU can't help a 1-round grid).
// ---------------------------------------------------------------------------
__global__ __launch_bounds__(512, 2) void gemm_out_kernel(
    const unsigned short* __restrict__ A, const unsigned short* __restrict__ BT,
    const float* __restrict__ bias, float* __restrict__ C) {
  __shared__ __align__(16) unsigned char smem[147456];
  unsigned short* smemS = (unsigned short*)smem;

  const int tid = threadIdx.x;
  const int wave = tid >> 6, lane = tid & 63;
  const int Q4 = lane >> 4, L = lane & 15;
  const int wr = wave >> 2, wc = wave & 3;

  const int flat = blockIdx.y * 8 + blockIdx.x;
  const int swz = (flat & 7) * 32 + (flat >> 3);
  const int m0 = (swz >> 3) * 256, n0 = (swz & 7) * 128;

  floatx4 acc[8][2];
  core256x128(A, BT, smemS, m0, n0, acc);

#pragma unroll
  for (int mt = 0; mt < 8; ++mt) {
#pragma unroll
    for (int nt = 0; nt < 2; ++nt) {
      int nc = n0 + wc * 32 + nt * 16 + L;
      float bv = bias[nc];
#pragma unroll
      for (int r = 0; r < 4; ++r) {
        int m = m0 + wr * 128 + mt * 16 + Q4 * 4 + r;
        C[(size_t)m * DMODEL + nc] = acc[mt][nt][r] + bv;
      }
    }
  }
}

#undef STAGE_TILE
#undef RD_A
#undef RD_B
#undef CLUSTER
#undef K32_STAGE
#undef G_BAR
#undef G_LGKM0

// ---------------------------------------------------------------------------
// Flash attention, SWAPPED-QK^T (T12) + ILP-INTERLEAVED COMPUTE.
// [BEST MEASURED: 77.8us, MfmaUtil 43.4, VALUBusy 49.6, 0 bank conflicts,
// FETCH 25 GB. R11's cross-kc2 hoist spilled (VGPR stayed 64, scratch
// traffic +9GB fetch) — per-qs interleave with no setprio fences is the
// allocator-friendly sweet spot.]
// LDS 32KB, grid 512, 8 waves, 2 blocks/CU.
// ---------------------------------------------------------------------------
__global__ __launch_bounds__(512, 4) void attn_kernel(
    const unsigned short* __restrict__ Qb, const unsigned short* __restrict__ Kb,
    const unsigned short* __restrict__ Vtg, unsigned short* __restrict__ Op) {
  __shared__ __align__(16) unsigned short Ks[2][64 * 64];
  __shared__ __align__(16) unsigned short Vs[2][64 * 64];
  const int tid = threadIdx.x;
  const int wave = tid >> 6, lane = tid & 63;   // wave 0..7
  const int quad = lane >> 4, l16 = lane & 15;
  const int bh = blockIdx.x & 63, qt = blockIdx.x >> 6;  // qt 0..7
  const size_t base = (size_t)bh * SEQ * DHEAD;
  const int lrow = lane >> 3, ls = lane & 7;
  const int dblk = ls ^ (lrow & 7);
  const int sw = l16 & 7;

  const unsigned short* kbase = Kb + base;
  const unsigned short* vbase = Vtg + base;
  const int rowS = wave * 8 + lrow;  // staging row (chunk = wave)

  short8 onesf;
#pragma unroll
  for (int i = 0; i < 8; ++i) onesf[i] = (short)0x3F80;  // bf16 1.0

  short8 qf[2][2];
#pragma unroll
  for (int qs = 0; qs < 2; ++qs) {
    int qrow = qt * 256 + wave * 32 + qs * 16 + l16;
    qf[qs][0] = *(const short8*)(Qb + base + (size_t)qrow * DHEAD + quad * 8);
    qf[qs][1] =
        *(const short8*)(Qb + base + (size_t)qrow * DHEAD + 32 + quad * 8);
  }

  floatx4 o[2][4], lacc[2];
#pragma unroll
  for (int qs = 0; qs < 2; ++qs) {
    lacc[qs] = (floatx4){0.f, 0.f, 0.f, 0.f};
#pragma unroll
    for (int dt = 0; dt < 4; ++dt) o[qs][dt] = (floatx4){0.f, 0.f, 0.f, 0.f};
  }

#define STAGE(buf, kc)                                                         \
  do {                                                                         \
    async_ld16(kbase + (size_t)((kc)*64 + rowS) * DHEAD + dblk * 8,            \
               &Ks[buf][wave * 512]);                                          \
    async_ld16(vbase + (size_t)rowS * SEQ + (kc)*64 + dblk * 8,                \
               &Vs[buf][wave * 512]);                                          \
  } while (0)

#define COMPUTE(buf)                                                           \
  do {                                                                         \
    _Pragma("unroll") for (int kc2 = 0; kc2 < 2; ++kc2) {                      \
      const int krow = kc2 * 32;                                               \
      short8 kf00 =                                                            \
          *(short8*)(&Ks[buf][0] + (krow + l16) * 64 + ((quad ^ sw) * 8));     \
      short8 kf01 = *(short8*)(&Ks[buf][0] + (krow + l16) * 64 +               \
                               (((4 + quad) ^ sw) * 8));                       \
      short8 kf10 = *(short8*)(&Ks[buf][0] + (krow + 16 + l16) * 64 +          \
                               ((quad ^ sw) * 8));                             \
      short8 kf11 = *(short8*)(&Ks[buf][0] + (krow + 16 + l16) * 64 +          \
                               (((4 + quad) ^ sw) * 8));                       \
      short8 vf[4];                                                            \
      _Pragma("unroll") for (int dt = 0; dt < 4; ++dt) vf[dt] =                \
          *(short8*)(&Vs[buf][0] + (dt * 16 + l16) * 64 +                      \
                     (((kc2 * 4 + quad) ^ sw) * 8));                           \
      floatx4 s0[2], s1[2];                                                    \
      _Pragma("unroll") for (int qs = 0; qs < 2; ++qs) {                       \
        s0[qs] = (floatx4){0.f, 0.f, 0.f, 0.f};                                \
        s1[qs] = (floatx4){0.f, 0.f, 0.f, 0.f};                                \
        s0[qs] = __builtin_amdgcn_mfma_f32_16x16x32_bf16(kf00, qf[qs][0],      \
                                                         s0[qs], 0, 0, 0);     \
        s0[qs] = __builtin_amdgcn_mfma_f32_16x16x32_bf16(kf01, qf[qs][1],      \
                                                         s0[qs], 0, 0, 0);     \
        s1[qs] = __builtin_amdgcn_mfma_f32_16x16x32_bf16(kf10, qf[qs][0],      \
                                                         s1[qs], 0, 0, 0);     \
        s1[qs] = __builtin_amdgcn_mfma_f32_16x16x32_bf16(kf11, qf[qs][1],      \
                                                         s1[qs], 0, 0, 0);     \
      }                                                                        \
      short8 pf[2];                                                            \
      _Pragma("unroll") for (int qs = 0; qs < 2; ++qs) {                       \
        union { short8 s8; u32 u[4]; } pu;                                     \
        _Pragma("unroll") for (int r = 0; r < 4; ++r) {                        \
          pu.u[r] = pack_bf16(fast_exp2(s0[qs][r]), fast_exp2(s1[qs][r]));     \
        }                                                                      \
        pf[qs] = pu.s8;                                                        \
      }                                                                        \
      _Pragma("unroll") for (int qs = 0; qs < 2; ++qs) {                       \
        lacc[qs] = __builtin_amdgcn_mfma_f32_16x16x32_bf16(pf[qs], onesf,      \
                                                           lacc[qs], 0, 0, 0); \
        _Pragma("unroll") for (int dt = 0; dt < 4; ++dt) o[qs][dt] =           \
            __builtin_amdgcn_mfma_f32_16x16x32_bf16(pf[qs], vf[dt],            \
                                                    o[qs][dt], 0, 0, 0);       \
      }                                                                        \
    }                                                                          \
  } while (0)

  STAGE(0, 0);
  for (int kc = 0; kc < SEQ / 64; kc += 2) {
    __syncthreads();  // buf0 loads complete; all waves done reading buf1
    if (kc + 1 < SEQ / 64) STAGE(1, kc + 1);
    COMPUTE(0);
    __syncthreads();  // buf1 loads complete; all waves done reading buf0
    if (kc + 2 < SEQ / 64) STAGE(0, kc + 2);
    COMPUTE(1);
  }
#undef STAGE
#undef COMPUTE

  const int b = bh >> 4, h = bh & 15;
#pragma unroll
  for (int qs = 0; qs < 2; ++qs) {
#pragma unroll
    for (int r = 0; r < 4; ++r) {
      float inv = 1.f / lacc[qs][r];
      int n = qt * 256 + wave * 32 + qs * 16 + quad * 4 + r;
      size_t rowbase = ((size_t)(b * SEQ + n)) * DMODEL + h * DHEAD;
#pragma unroll
      for (int dt = 0; dt < 4; ++dt)
        Op[rowbase + dt * 16 + l16] = f2bf(o[qs][dt][r] * inv);
    }
  }
}

extern "C" void kernel_launch(void* const* d_in, const int* in_sizes, int n_in,
                              void* d_out, int out_size, void* d_ws,
                              size_t ws_size, hipStream_t stream) {
  const float* x = (const float*)d_in[0];
  const float* w_qkv = (const float*)d_in[1];
  const float* w_out = (const float*)d_in[2];
  const float* b_out = (const float*)d_in[3];
  float* out = (float*)d_out;

  unsigned short* ws = (unsigned short*)d_ws;
  unsigned short* xb = ws;                         // 8388608
  unsigned short* wqkvT = xb + 8388608;            // 3145728  [3072][1024]
  unsigned short* woutT = wqkvT + 3145728;         // 1048576  [1024][1024]
  unsigned short* qb = woutT + 1048576;            // [B,H,N,64] (pre-scaled)
  unsigned short* kb = qb + QKV_ELEMS;             // [B,H,N,64]
  unsigned short* vtg = kb + QKV_ELEMS;            // [B,H,64,N] permuted cols
  unsigned short* op = vtg + QKV_ELEMS;            // [B,N,1024]

  prep_kernel<<<dim3(12288), dim3(256), 0, stream>>>(x, w_qkv, w_out, xb,
                                                     wqkvT, woutT);
  gemm_qkv_kernel<<<dim3(24, 32), dim3(512), 0, stream>>>(xb, wqkvT, qb, vtg);
  attn_kernel<<<dim3(512), dim3(512), 0, stream>>>(qb, kb, vtg, op);
  gemm_out_kernel<<<dim3(8, 32), dim3(512), 0, stream>>>(op, woutT, b_out, out);
}